// Round 3
// baseline (375.519 us; speedup 1.0000x reference)
//
#include <hip/hip_runtime.h>

// Problem constants
#define BATCH 512
#define HWIMG 78400      // 280*280
#define WROW  280
#define KSZ   28
#define PNUM  100        // 10x10 patches
#define FNUM  16
#define ONUM  10

__global__ __launch_bounds__(256) void init_out(const float* __restrict__ dec_b,
                                                float* __restrict__ out) {
    int i = blockIdx.x * 256 + threadIdx.x;
    if (i < BATCH * ONUM) out[i] = dec_b[i % ONUM];
}

// Block: one patch p, 64 batches, 16 filters. 256 threads = kg(8) x fg(4) x bg(8).
// Per-thread tile: 8 batches x 4 filters (128 FMA : 12 VMEM per k-row).
// Both x and w register-double-buffered; launch_bounds(256,3) -> ~170 VGPR cap
// so the pipeline actually allocates (R1's 40-reg cap killed it).
__global__ __launch_bounds__(256, 3) void lcn_fused(
    const float* __restrict__ x,      // (512,1,280,280)
    const float* __restrict__ weight, // (1600,1,28,28)  index (f*100+p)*784
    const float* __restrict__ bias,   // (1600,1)        index  f*100+p
    const float* __restrict__ dec_w,  // (10,1600)       index  o*1600+f*100+p
    float* __restrict__ out)          // (512,10) pre-initialized with dec_b
{
    const int t  = threadIdx.x;
    const int kg = t & 7;           // k-slice group (lane bits 0..2)
    const int fg = (t >> 3) & 3;    // filter group  (lane bits 3..4)
    const int bg = t >> 5;          // batch group   0..7
    const int bx = blockIdx.x;
    const int p  = bx >> 3;         // 0..99
    const int bt = bx & 7;          // batch tile 0..7 (64 batches each)
    const int pr = p / 10, pc = p % 10;
    const int b0 = bt * 64 + bg * 8;

    // kg==7 would read k=28..31 (past the patch row): clamp to 24, zero later.
    const int kq = (kg < 7) ? kg * 4 : 24;

    const float* xb = x + (size_t)b0 * HWIMG + (size_t)pr * 28 * WROW + pc * 28 + kq;
    const float* wb = weight + (size_t)((fg * 4) * PNUM + p) * 784 + kq;  // filter stride 100*784

    float acc[8][4];
#pragma unroll
    for (int i = 0; i < 8; ++i)
#pragma unroll
        for (int j = 0; j < 4; ++j) acc[i][j] = 0.f;

    // Register double-buffer for both x and w.
    float4 av[8], bv[8], wv[4], uv[4];
#pragma unroll
    for (int i = 0; i < 8; ++i)
        av[i] = *reinterpret_cast<const float4*>(xb + (size_t)i * HWIMG);
#pragma unroll
    for (int j = 0; j < 4; ++j)
        wv[j] = *reinterpret_cast<const float4*>(wb + (size_t)j * (PNUM * 784));

#pragma unroll 2
    for (int kr = 0; kr < KSZ; ++kr) {
        if (kr + 1 < KSZ) {
#pragma unroll
            for (int i = 0; i < 8; ++i)
                bv[i] = *reinterpret_cast<const float4*>(xb + (size_t)i * HWIMG + (kr + 1) * WROW);
#pragma unroll
            for (int j = 0; j < 4; ++j)
                uv[j] = *reinterpret_cast<const float4*>(wb + (size_t)j * (PNUM * 784) + (kr + 1) * KSZ);
        }
#pragma unroll
        for (int i = 0; i < 8; ++i) {
#pragma unroll
            for (int j = 0; j < 4; ++j) {
                acc[i][j] = fmaf(av[i].x, wv[j].x, acc[i][j]);
                acc[i][j] = fmaf(av[i].y, wv[j].y, acc[i][j]);
                acc[i][j] = fmaf(av[i].z, wv[j].z, acc[i][j]);
                acc[i][j] = fmaf(av[i].w, wv[j].w, acc[i][j]);
            }
        }
#pragma unroll
        for (int i = 0; i < 8; ++i) av[i] = bv[i];
#pragma unroll
        for (int j = 0; j < 4; ++j) wv[j] = uv[j];
    }

    // kg==7 computed on duplicated data: zero it.
    const float km = (kg < 7) ? 1.f : 0.f;
#pragma unroll
    for (int i = 0; i < 8; ++i)
#pragma unroll
        for (int j = 0; j < 4; ++j) acc[i][j] *= km;

    // Reduce over kg (lane bits 0..2) — butterfly; all lanes end with the sum.
#pragma unroll
    for (int d = 1; d < 8; d <<= 1)
#pragma unroll
        for (int i = 0; i < 8; ++i)
#pragma unroll
            for (int j = 0; j < 4; ++j)
                acc[i][j] += __shfl_xor(acc[i][j], d, 64);

    // bias + relu
    float y[8][4];
#pragma unroll
    for (int j = 0; j < 4; ++j) {
        const float bs = bias[(fg * 4 + j) * PNUM + p];
#pragma unroll
        for (int i = 0; i < 8; ++i) {
            float v = acc[i][j] + bs;
            y[i][j] = v > 0.f ? v : 0.f;
        }
    }

    // Decoder: split the 10 outputs across kg lanes 0..4 (2 outputs each).
    float po[8][2];
    const int  o0  = kg * 2;
    const bool act = (kg < 5);
    if (act) {
        float dwv[4][2];
#pragma unroll
        for (int j = 0; j < 4; ++j)
#pragma unroll
            for (int oo = 0; oo < 2; ++oo)
                dwv[j][oo] = dec_w[(size_t)(o0 + oo) * (PNUM * FNUM) + (fg * 4 + j) * PNUM + p];
#pragma unroll
        for (int i = 0; i < 8; ++i)
#pragma unroll
            for (int oo = 0; oo < 2; ++oo) {
                float s = 0.f;
#pragma unroll
                for (int j = 0; j < 4; ++j) s = fmaf(y[i][j], dwv[j][oo], s);
                po[i][oo] = s;
            }
    } else {
#pragma unroll
        for (int i = 0; i < 8; ++i) { po[i][0] = 0.f; po[i][1] = 0.f; }
    }

    // Reduce over fg (lane bits 3..4); kg bits preserved so zero lanes stay isolated.
#pragma unroll
    for (int d = 8; d < 32; d <<= 1)
#pragma unroll
        for (int i = 0; i < 8; ++i)
#pragma unroll
            for (int oo = 0; oo < 2; ++oo)
                po[i][oo] += __shfl_xor(po[i][oo], d, 64);

    if (act && fg == 0) {
#pragma unroll
        for (int i = 0; i < 8; ++i)
#pragma unroll
            for (int oo = 0; oo < 2; ++oo)
                atomicAdd(&out[(size_t)(b0 + i) * ONUM + o0 + oo], po[i][oo]);
    }
}

extern "C" void kernel_launch(void* const* d_in, const int* in_sizes, int n_in,
                              void* d_out, int out_size, void* d_ws, size_t ws_size,
                              hipStream_t stream) {
    const float* x     = (const float*)d_in[0];
    const float* w     = (const float*)d_in[1];
    const float* bias  = (const float*)d_in[2];
    const float* dec_w = (const float*)d_in[3];
    const float* dec_b = (const float*)d_in[4];
    float* out = (float*)d_out;

    init_out<<<(BATCH * ONUM + 255) / 256, 256, 0, stream>>>(dec_b, out);
    lcn_fused<<<(BATCH / 64) * PNUM, 256, 0, stream>>>(x, w, bias, dec_w, out);
}

// Round 4
// 256.305 us; speedup vs baseline: 1.4651x; 1.4651x over previous
//
#include <hip/hip_runtime.h>
#include <stdint.h>

// Problem constants
#define BATCH 512
#define HWIMG 78400      // 280*280
#define WROW  280
#define KSZ   28
#define PNUM  100        // 10x10 patches
#define FNUM  16
#define ONUM  10

#define BT    64         // batches per block
#define CH    7          // k-chunks of 4 rows (28 rows total)
#define XF4   (BT * 28)  // 1792 float4 per x buffer (64 b x 4 rows x 7 f4)
#define WF4   (FNUM * 28) // 448 float4 per w buffer

typedef __attribute__((address_space(1))) const void cg_void;
typedef __attribute__((address_space(3))) void lds_void;

__global__ __launch_bounds__(256) void init_out(const float* __restrict__ dec_b,
                                                float* __restrict__ out) {
    int i = blockIdx.x * 256 + threadIdx.x;
    if (i < BATCH * ONUM) out[i] = dec_b[i % ONUM];
}

// Block: one patch p, 64 batches, 16 filters. 256 threads = kg(8) x fg(4) x bg(8).
// x and w staged via global_load_lds (async DMA, no VGPR cost), LDS double-buffered.
// Raw s_barrier + manual vmcnt(9) keeps next chunk's DMA in flight across barrier.
__global__ __launch_bounds__(256) void lcn_fused(
    const float* __restrict__ x,      // (512,1,280,280)
    const float* __restrict__ weight, // (1600,1,28,28)  index (f*100+p)*784
    const float* __restrict__ bias,   // (1600,1)        index  f*100+p
    const float* __restrict__ dec_w,  // (10,1600)       index  o*1600+f*100+p
    float* __restrict__ out)          // (512,10) pre-initialized with dec_b
{
    __shared__ float4 lx[2][XF4];   // [buf][b*28 + r*7 + c4]
    __shared__ float4 lw[2][WF4];   // [buf][f*28 + r*7 + c4]

    const int t  = threadIdx.x;
    const int kg = t & 7;           // k-slice (lane bits 0..2): column f4 within row
    const int fg = (t >> 3) & 3;    // filter group (lane bits 3..4)
    const int bg = t >> 5;          // batch group 0..7
    const int bx = blockIdx.x;
    const int p  = bx >> 3;         // 0..99 (8 consecutive blocks share p -> warm W in L2)
    const int bt = bx & 7;
    const int pr = p / 10, pc = p % 10;
    const int b0 = bt * BT;

    // ---- DMA source pointers. x: 7 sweeps of 256 f4; flat idx = b*28 + r*7 + c4.
    const float* xs[7];
#pragma unroll
    for (int s = 0; s < 7; ++s) {
        int idx = s * 256 + t;
        int b  = idx / 28, rf = idx % 28;
        int r0 = rf / 7,   c4 = rf % 7;
        xs[s] = x + (size_t)(b0 + b) * HWIMG + (size_t)(pr * 28 + r0) * WROW
                  + pc * 28 + c4 * 4;
    }
    // w: 448 f4 = 2 sweeps; sweep1 wave3 duplicates wave2's slots (same data, benign)
    // so every wave issues exactly 9 DMA ops per chunk (uniform vmcnt bookkeeping).
    const int wi1 = 256 + (t < 192 ? t : t - 64);
    const float* ws0;
    const float* ws1;
    {
        int f = t / 28, rf = t % 28;
        ws0 = weight + ((size_t)(f * PNUM + p)) * 784 + rf * 4;
        f = wi1 / 28; rf = wi1 % 28;
        ws1 = weight + ((size_t)(f * PNUM + p)) * 784 + rf * 4;
    }

    auto issue_chunk = [&](int cc, int bb) {
#pragma unroll
        for (int s = 0; s < 7; ++s)
            __builtin_amdgcn_global_load_lds((cg_void*)(xs[s] + (size_t)cc * 4 * WROW),
                                             (lds_void*)&lx[bb][s * 256 + t], 16, 0, 0);
        __builtin_amdgcn_global_load_lds((cg_void*)(ws0 + (size_t)cc * 112),
                                         (lds_void*)&lw[bb][t], 16, 0, 0);
        __builtin_amdgcn_global_load_lds((cg_void*)(ws1 + (size_t)cc * 112),
                                         (lds_void*)&lw[bb][wi1], 16, 0, 0);
    };

    issue_chunk(0, 0);
    issue_chunk(1, 1);

    float acc[8][4];
#pragma unroll
    for (int i = 0; i < 8; ++i)
#pragma unroll
        for (int j = 0; j < 4; ++j) acc[i][j] = 0.f;

    const int kge = (kg < 7) ? kg : 0;   // kg==7 duplicates kg==0, masked later

#pragma unroll
    for (int c = 0; c < CH; ++c) {
        const int buf = c & 1;
        // Wait for chunk c's 9 DMA ops (oldest); chunk c+1's 9 stay in flight.
        if (c < CH - 1) asm volatile("s_waitcnt vmcnt(9)" ::: "memory");
        else            asm volatile("s_waitcnt vmcnt(0)" ::: "memory");
        __builtin_amdgcn_s_barrier();
        asm volatile("" ::: "memory");

#pragma unroll
        for (int m = 0; m < 4; ++m) {          // 4 rows per chunk
            float4 wv[4];
#pragma unroll
            for (int j = 0; j < 4; ++j)
                wv[j] = lw[buf][(fg * 4 + j) * 28 + m * 7 + kge];
#pragma unroll
            for (int i = 0; i < 8; ++i) {
                float4 av = lx[buf][(bg * 8 + i) * 28 + m * 7 + kge];
#pragma unroll
                for (int j = 0; j < 4; ++j) {
                    acc[i][j] = fmaf(av.x, wv[j].x, acc[i][j]);
                    acc[i][j] = fmaf(av.y, wv[j].y, acc[i][j]);
                    acc[i][j] = fmaf(av.z, wv[j].z, acc[i][j]);
                    acc[i][j] = fmaf(av.w, wv[j].w, acc[i][j]);
                }
            }
        }

        asm volatile("" ::: "memory");
        __builtin_amdgcn_s_barrier();        // all waves done reading buf
        if (c + 2 < CH) issue_chunk(c + 2, buf);
    }

    // kg==7 computed duplicated data: zero it.
    const float km = (kg < 7) ? 1.f : 0.f;
#pragma unroll
    for (int i = 0; i < 8; ++i)
#pragma unroll
        for (int j = 0; j < 4; ++j) acc[i][j] *= km;

    // Reduce over kg (lane bits 0..2) — butterfly; all lanes end with the sum.
#pragma unroll
    for (int d = 1; d < 8; d <<= 1)
#pragma unroll
        for (int i = 0; i < 8; ++i)
#pragma unroll
            for (int j = 0; j < 4; ++j)
                acc[i][j] += __shfl_xor(acc[i][j], d, 64);

    // bias + relu
    float y[8][4];
#pragma unroll
    for (int j = 0; j < 4; ++j) {
        const float bs = bias[(fg * 4 + j) * PNUM + p];
#pragma unroll
        for (int i = 0; i < 8; ++i) {
            float v = acc[i][j] + bs;
            y[i][j] = v > 0.f ? v : 0.f;
        }
    }

    // Decoder: split the 10 outputs across kg lanes 0..4 (2 outputs each).
    float po[8][2];
    const int  o0  = kg * 2;
    const bool act = (kg < 5);
    if (act) {
        float dwv[4][2];
#pragma unroll
        for (int j = 0; j < 4; ++j)
#pragma unroll
            for (int oo = 0; oo < 2; ++oo)
                dwv[j][oo] = dec_w[(size_t)(o0 + oo) * (PNUM * FNUM) + (fg * 4 + j) * PNUM + p];
#pragma unroll
        for (int i = 0; i < 8; ++i)
#pragma unroll
            for (int oo = 0; oo < 2; ++oo) {
                float s = 0.f;
#pragma unroll
                for (int j = 0; j < 4; ++j) s = fmaf(y[i][j], dwv[j][oo], s);
                po[i][oo] = s;
            }
    } else {
#pragma unroll
        for (int i = 0; i < 8; ++i) { po[i][0] = 0.f; po[i][1] = 0.f; }
    }

    // Reduce over fg (lane bits 3..4); kg bits preserved so zero lanes stay isolated.
#pragma unroll
    for (int d = 8; d < 32; d <<= 1)
#pragma unroll
        for (int i = 0; i < 8; ++i)
#pragma unroll
            for (int oo = 0; oo < 2; ++oo)
                po[i][oo] += __shfl_xor(po[i][oo], d, 64);

    if (act && fg == 0) {
#pragma unroll
        for (int i = 0; i < 8; ++i)
#pragma unroll
            for (int oo = 0; oo < 2; ++oo)
                atomicAdd(&out[(size_t)(b0 + bg * 8 + i) * ONUM + o0 + oo], po[i][oo]);
    }
}

extern "C" void kernel_launch(void* const* d_in, const int* in_sizes, int n_in,
                              void* d_out, int out_size, void* d_ws, size_t ws_size,
                              hipStream_t stream) {
    const float* x     = (const float*)d_in[0];
    const float* w     = (const float*)d_in[1];
    const float* bias  = (const float*)d_in[2];
    const float* dec_w = (const float*)d_in[3];
    const float* dec_b = (const float*)d_in[4];
    float* out = (float*)d_out;

    init_out<<<(BATCH * ONUM + 255) / 256, 256, 0, stream>>>(dec_b, out);
    lcn_fused<<<(BATCH / BT) * PNUM, 256, 0, stream>>>(x, w, bias, dec_w, out);
}